// Round 11
// baseline (119.534 us; speedup 1.0000x reference)
//
#include <hip/hip_runtime.h>

#define NNODES 196608
#define NH 9
#define F 64
#define K_TOT 576      // NH * F
#define KSTEPS 18      // K_TOT / 32
#define LN_EPS 1e-5f

typedef __attribute__((ext_vector_type(8))) short short8v;
typedef __attribute__((ext_vector_type(4))) float f32x4;

__device__ __forceinline__ unsigned short f2bf(float f) {
    unsigned int u = __float_as_uint(f);
    u += 0x7fff + ((u >> 16) & 1);          // round-to-nearest-even
    return (unsigned short)(u >> 16);
}
__device__ __forceinline__ float silu_f(float z) { return z / (1.0f + __expf(-z)); }

// Async global->LDS, 16 B per lane. Dest is wave-uniform base + lane*16 (linear).
__device__ __forceinline__ void gload_lds16(const void* g, void* l) {
    __builtin_amdgcn_global_load_lds((__attribute__((address_space(1))) void*)g,
                                     (__attribute__((address_space(3))) void*)l,
                                     16, 0, 0);
}

// Fragment-ordered bf16 weights: element (o,k) of B goes to
// Wt[((s*4 + w)*64 + lg*16 + l16)*8 + j] -> a wave's bfrag load is 64 lanes x
// 16B contiguous (16 CLs vs 64 for o-major).
__global__ __launch_bounds__(256) void prep_wt(const float* __restrict__ W1,
                                               const float* __restrict__ W2,
                                               unsigned short* __restrict__ Wt1,
                                               unsigned short* __restrict__ Wt2) {
    int tid = blockIdx.x * 256 + threadIdx.x;
    if (tid >= F * K_TOT) return;
    int o = tid & 63, k = tid >> 6;          // consecutive tid -> consecutive o (coalesced read)
    int s = k >> 5, lg = (k & 31) >> 3, j = k & 7;
    int w = o >> 4, l16 = o & 15;
    int dst = ((s * 4 + w) * 64 + lg * 16 + l16) * 8 + j;
    Wt1[dst] = f2bf(W1[(size_t)k * F + o]);
    Wt2[dst] = f2bf(W2[(size_t)k * F + o]);
}

// LN + SiLU, f32 in -> bf16 out. 16 threads per row, float4 per thread.
__global__ __launch_bounds__(256) void ln1_silu(const float* __restrict__ x,
                                                const float* __restrict__ w,
                                                const float* __restrict__ b,
                                                unsigned short* __restrict__ out) {
    const int t = threadIdx.x;
    const int row = blockIdx.x * 16 + (t >> 4);
    const int fl = (t & 15) * 4;
    const float4 v = *(const float4*)(x + (size_t)row * F + fl);
    float s = v.x + v.y + v.z + v.w;
    float ss = v.x * v.x + v.y * v.y + v.z * v.z + v.w * v.w;
#pragma unroll
    for (int o = 8; o; o >>= 1) { s += __shfl_xor(s, o); ss += __shfl_xor(ss, o); }
    const float mu = s * (1.0f / F);
    const float rstd = rsqrtf(ss * (1.0f / F) - mu * mu + LN_EPS);
    const float4 wv = *(const float4*)(w + fl);
    const float4 bv = *(const float4*)(b + fl);
    ushort4 o4;
    o4.x = f2bf(silu_f((v.x - mu) * rstd * wv.x + bv.x));
    o4.y = f2bf(silu_f((v.y - mu) * rstd * wv.y + bv.y));
    o4.z = f2bf(silu_f((v.z - mu) * rstd * wv.z + bv.z));
    o4.w = f2bf(silu_f((v.w - mu) * rstd * wv.w + bv.w));
    *(ushort4*)(out + (size_t)row * F + fl) = o4;
}

// Round-11: FULL-DEPTH staging. 9 LDS buffers (72 KB); each wave issues all 18
// global_load_lds in the prologue (one pipelined latency payment per block),
// then consumes head h behind s_waitcnt vmcnt(16-2h) + s_barrier. In-flight
// bytes/CU: ~60 KB (depth-3) -> ~144 KB (2 blocks x 4 waves x 18 KB).
// vmcnt safety is positional: #ops issued after stage(h) >= 16-2h, so the
// literal wait can only over-cover. bfrag preloaded from fragment-ordered Wt
// and pinned opaque (round-10). LDS caps residency at 2 blocks/CU; that's the
// trade: fewer waves, 2.4x the in-flight gather bytes (the thing Little's law
// actually pays for at ~600-900cy random-gather latency).
template<int FINAL>
__global__ __launch_bounds__(256) __attribute__((amdgpu_waves_per_eu(2, 4)))
void gconv_mfma(
    const unsigned short* __restrict__ h,
    const int* __restrict__ adjc,
    const unsigned short* __restrict__ Wt,
    const float* __restrict__ bias,
    const float* __restrict__ lnw, const float* __restrict__ lnb,
    const float* __restrict__ xres,
    void* __restrict__ outv)
{
    __shared__ __align__(16) char smem[NH * 8192];      // 72 KB: 9 A-tile buffers
    unsigned short* tile = (unsigned short*)smem;        // [9][64 rows][64] bf16
    float (*T)[68] = (float (*)[68])smem;                // epilogue reuse (17.4 KB)

    const int wave = threadIdx.x >> 6;
    const int lane = threadIdx.x & 63;
    const int l16 = lane & 15, lg = lane >> 4;
    const int nodeBase = blockIdx.x * 64;

    // Staging geometry: instr j (=2w, 2w+1) covers rows 8j..8j+7, 8 chunks of 16 B.
    const int srow = lane >> 3;              // row within group of 8 (== row&7)
    const int sswz = (lane & 7) ^ srow;      // pre-swizzled global chunk for this lane
    const int rA = wave * 16 + srow;
    const int rB = rA + 8;

    int idxA[NH], idxB[NH];
    {
        const int* a0 = adjc + (size_t)(nodeBase + rA) * NH;
        const int* a1 = adjc + (size_t)(nodeBase + rB) * NH;
#pragma unroll
        for (int hh = 0; hh < NH; ++hh) { idxA[hh] = a0[hh]; idxB[hh] = a1[hh]; }
    }

    // B fragments: coalesced preload (fragment-ordered Wt), then pinned resident.
    short8v bfrag[KSTEPS];
    {
        const short8v* wp = (const short8v*)(Wt) + (size_t)wave * 64 + lane;
#pragma unroll
        for (int s = 0; s < KSTEPS; ++s) bfrag[s] = wp[(size_t)s * 256];
    }
#pragma unroll
    for (int s = 0; s < KSTEPS; ++s)
        asm volatile("" : "+v"(bfrag[s]));   // opaque: cannot be remat'd/sunk

    f32x4 acc[4];
#pragma unroll
    for (int m = 0; m < 4; ++m) acc[m] = (f32x4){0.f, 0.f, 0.f, 0.f};

#define STAGE(BUF, HH)                                                         \
    do {                                                                       \
        gload_lds16(h + (size_t)idxA[HH] * F + sswz * 8,                       \
                    (char*)tile + (BUF) * 8192 + (2 * wave) * 1024);           \
        gload_lds16(h + (size_t)idxB[HH] * F + sswz * 8,                       \
                    (char*)tile + (BUF) * 8192 + (2 * wave + 1) * 1024);       \
    } while (0)

#define COMPUTE(BUF, HH)                                                       \
    _Pragma("unroll")                                                          \
    for (int m = 0; m < 4; ++m) {                                              \
        _Pragma("unroll")                                                      \
        for (int kh = 0; kh < 2; ++kh) {                                       \
            const short8v a = *(const short8v*)((char*)tile + (BUF) * 8192     \
                + (m * 16 + l16) * 128 + (((kh * 4 + lg) ^ (l16 & 7)) * 16));  \
            acc[m] = __builtin_amdgcn_mfma_f32_16x16x32_bf16(                  \
                a, bfrag[(HH) * 2 + kh], acc[m], 0, 0, 0);                     \
        }                                                                      \
    }

    // Prologue: issue ALL 18 stage loads (9 heads), head-ordered.
#pragma unroll
    for (int hh = 0; hh < NH; ++hh) STAGE(hh, hh);

    // Per head: wait own stage(h) via positional vmcnt, barrier, compute.
#define PHASE(HH, VN)                                                          \
    asm volatile("s_waitcnt vmcnt(" #VN ")" ::: "memory");                     \
    __builtin_amdgcn_s_barrier();                                              \
    COMPUTE(HH, HH);

    PHASE(0, 16) PHASE(1, 14) PHASE(2, 12) PHASE(3, 10) PHASE(4, 8)
    PHASE(5, 6)  PHASE(6, 4)  PHASE(7, 2)  PHASE(8, 0)
#undef PHASE
#undef STAGE
#undef COMPUTE

    __syncthreads();   // all compute reads done before tile region is reused as T

    // Epilogue: transpose via LDS. D layout: row(node)=m*16+lg*4+r, col(o)=wave*16+l16
#pragma unroll
    for (int m = 0; m < 4; ++m)
#pragma unroll
        for (int r = 0; r < 4; ++r)
            T[m * 16 + lg * 4 + r][wave * 16 + l16] = acc[m][r];
    __syncthreads();

    const int t = threadIdx.x;
    const int nl = t >> 2, q = t & 3;                // 4 threads per node, 16 outputs each
    const int node = nodeBase + nl;
    float v[16];
#pragma unroll
    for (int i = 0; i < 16; ++i) v[i] = T[nl][q * 16 + i] + bias[q * 16 + i];

    if (FINAL) {
        float* out = (float*)outv;
#pragma unroll
        for (int i4 = 0; i4 < 4; ++i4) {
            const float4 xr = *(const float4*)(xres + (size_t)node * F + q * 16 + i4 * 4);
            float4 ov;
            ov.x = v[i4 * 4 + 0] + xr.x; ov.y = v[i4 * 4 + 1] + xr.y;
            ov.z = v[i4 * 4 + 2] + xr.z; ov.w = v[i4 * 4 + 3] + xr.w;
            *(float4*)(out + (size_t)node * F + q * 16 + i4 * 4) = ov;
        }
    } else {
        float s = 0.f, ss = 0.f;
#pragma unroll
        for (int i = 0; i < 16; ++i) { s += v[i]; ss += v[i] * v[i]; }
        s += __shfl_xor(s, 1); ss += __shfl_xor(ss, 1);
        s += __shfl_xor(s, 2); ss += __shfl_xor(ss, 2);
        const float mu = s * (1.0f / F);
        const float rstd = rsqrtf(ss * (1.0f / F) - mu * mu + LN_EPS);
        unsigned short* out = (unsigned short*)outv;
        unsigned short ob[16];
#pragma unroll
        for (int i = 0; i < 16; ++i) {
            const int o = q * 16 + i;
            const float y = (v[i] - mu) * rstd * lnw[o] + lnb[o];
            ob[i] = f2bf(silu_f(y));
        }
#pragma unroll
        for (int c = 0; c < 2; ++c)
            *(short8v*)(out + (size_t)node * F + q * 16 + c * 8) = *(short8v*)(ob + c * 8);
    }
}

extern "C" void kernel_launch(void* const* d_in, const int* in_sizes, int n_in,
                              void* d_out, int out_size, void* d_ws, size_t ws_size,
                              hipStream_t stream)
{
    const float* x    = (const float*)d_in[0];
    const int*   adjc = (const int*)d_in[1];
    const float* ln1w = (const float*)d_in[2];
    const float* ln1b = (const float*)d_in[3];
    const float* W1   = (const float*)d_in[4];
    const float* b1   = (const float*)d_in[5];
    const float* ln2w = (const float*)d_in[6];
    const float* ln2b = (const float*)d_in[7];
    const float* W2   = (const float*)d_in[8];
    const float* b2   = (const float*)d_in[9];
    float* out = (float*)d_out;

    unsigned short* h1  = (unsigned short*)d_ws;              // 25.2 MB bf16
    unsigned short* h2  = h1 + (size_t)NNODES * F;            // 25.2 MB bf16
    unsigned short* Wt1 = h2 + (size_t)NNODES * F;            // 144 KB
    unsigned short* Wt2 = Wt1 + F * K_TOT;                    // 144 KB

    prep_wt<<<(F * K_TOT + 255) / 256, 256, 0, stream>>>(W1, W2, Wt1, Wt2);
    ln1_silu<<<NNODES / 16, 256, 0, stream>>>(x, ln1w, ln1b, h1);
    gconv_mfma<0><<<NNODES / 64, 256, 0, stream>>>(h1, adjc, Wt1, b1, ln2w, ln2b, nullptr, h2);
    gconv_mfma<1><<<NNODES / 64, 256, 0, stream>>>(h2, adjc, Wt2, b2, nullptr, nullptr, x, out);
}

// Round 12
// 108.534 us; speedup vs baseline: 1.1013x; 1.1013x over previous
//
#include <hip/hip_runtime.h>

#define NNODES 196608
#define NH 9
#define F 64
#define K_TOT 576      // NH * F
#define KSTEPS 18      // K_TOT / 32
#define LN_EPS 1e-5f

typedef __attribute__((ext_vector_type(8))) short short8v;
typedef __attribute__((ext_vector_type(4))) float f32x4;

__device__ __forceinline__ unsigned short f2bf(float f) {
    unsigned int u = __float_as_uint(f);
    u += 0x7fff + ((u >> 16) & 1);          // round-to-nearest-even
    return (unsigned short)(u >> 16);
}
__device__ __forceinline__ float bf2f(unsigned short u) {
    return __uint_as_float((unsigned int)u << 16);
}
__device__ __forceinline__ float silu_f(float z) { return z / (1.0f + __expf(-z)); }

// Async global->LDS, 16 B per lane. Dest is wave-uniform base + lane*16 (linear).
__device__ __forceinline__ void gload_lds16(const void* g, void* l) {
    __builtin_amdgcn_global_load_lds((__attribute__((address_space(1))) void*)g,
                                     (__attribute__((address_space(3))) void*)l,
                                     16, 0, 0);
}

// Fragment-ordered bf16 weights: element (o,k) of B goes to
// Wt[((s*4 + w)*64 + lg*16 + l16)*8 + j] -> a wave's bfrag load is 64 lanes x
// 16B contiguous (16 CLs vs 64 for o-major).
__global__ __launch_bounds__(256) void prep_wt(const float* __restrict__ W1,
                                               const float* __restrict__ W2,
                                               unsigned short* __restrict__ Wt1,
                                               unsigned short* __restrict__ Wt2) {
    int tid = blockIdx.x * 256 + threadIdx.x;
    if (tid >= F * K_TOT) return;
    int o = tid & 63, k = tid >> 6;          // consecutive tid -> consecutive o (coalesced read)
    int s = k >> 5, lg = (k & 31) >> 3, j = k & 7;
    int w = o >> 4, l16 = o & 15;
    int dst = ((s * 4 + w) * 64 + lg * 16 + l16) * 8 + j;
    Wt1[dst] = f2bf(W1[(size_t)k * F + o]);
    Wt2[dst] = f2bf(W2[(size_t)k * F + o]);
}

// LN + SiLU, f32 in -> bf16 out; optionally also emits raw x as bf16 (xbf) for
// gconv1's residual read (round-12: halves the 50MB xres stream in gconv1).
__global__ __launch_bounds__(256) void ln1_silu(const float* __restrict__ x,
                                                const float* __restrict__ w,
                                                const float* __restrict__ b,
                                                unsigned short* __restrict__ out,
                                                unsigned short* __restrict__ xbf) {
    const int t = threadIdx.x;
    const int row = blockIdx.x * 16 + (t >> 4);
    const int fl = (t & 15) * 4;
    const float4 v = *(const float4*)(x + (size_t)row * F + fl);
    float s = v.x + v.y + v.z + v.w;
    float ss = v.x * v.x + v.y * v.y + v.z * v.z + v.w * v.w;
#pragma unroll
    for (int o = 8; o; o >>= 1) { s += __shfl_xor(s, o); ss += __shfl_xor(ss, o); }
    const float mu = s * (1.0f / F);
    const float rstd = rsqrtf(ss * (1.0f / F) - mu * mu + LN_EPS);
    const float4 wv = *(const float4*)(w + fl);
    const float4 bv = *(const float4*)(b + fl);
    ushort4 o4;
    o4.x = f2bf(silu_f((v.x - mu) * rstd * wv.x + bv.x));
    o4.y = f2bf(silu_f((v.y - mu) * rstd * wv.y + bv.y));
    o4.z = f2bf(silu_f((v.z - mu) * rstd * wv.z + bv.z));
    o4.w = f2bf(silu_f((v.w - mu) * rstd * wv.w + bv.w));
    *(ushort4*)(out + (size_t)row * F + fl) = o4;
    if (xbf) {
        ushort4 xq;
        xq.x = f2bf(v.x); xq.y = f2bf(v.y); xq.z = f2bf(v.z); xq.w = f2bf(v.w);
        *(ushort4*)(xbf + (size_t)row * F + fl) = xq;
    }
}

// Round-10 structure (best: 49.7us/gconv): cooperative gload_lds staging,
// XOR-swizzle both sides (rule #21), fragment-ordered Wt preloaded+pinned
// opaque, depth-3 prefetch with counted vmcnt. Round-11 lesson: deeper staging
// REGRESSED -> beyond-L2 random-fetch service saturates at ~2.6 TB/s; only
// traffic reduction helps now. Round-12: XBF residual read as bf16 (-25MB
// gconv1 fetch); waves_per_eu max 3->4 (allows a 4th block/CU at 32KB LDS).
template<int FINAL, int XBF>
__global__ __launch_bounds__(256) __attribute__((amdgpu_waves_per_eu(3, 4)))
void gconv_mfma(
    const unsigned short* __restrict__ h,
    const int* __restrict__ adjc,
    const unsigned short* __restrict__ Wt,
    const float* __restrict__ bias,
    const float* __restrict__ lnw, const float* __restrict__ lnb,
    const void* __restrict__ xres,
    void* __restrict__ outv)
{
    __shared__ __align__(16) char smem[4 * 8192];       // 32 KB: 4 A-tile buffers
    unsigned short* tile = (unsigned short*)smem;        // [4][64 rows][64] bf16
    float (*T)[68] = (float (*)[68])smem;                // epilogue reuse (17.4 KB)

    const int wave = threadIdx.x >> 6;
    const int lane = threadIdx.x & 63;
    const int l16 = lane & 15, lg = lane >> 4;
    const int nodeBase = blockIdx.x * 64;

    // Staging geometry: instr j (=2w, 2w+1) covers rows 8j..8j+7, 8 chunks of 16 B.
    const int srow = lane >> 3;              // row within group of 8 (== row&7)
    const int sswz = (lane & 7) ^ srow;      // pre-swizzled global chunk for this lane
    const int rA = wave * 16 + srow;
    const int rB = rA + 8;

    int idxA[NH], idxB[NH];
    {
        const int* a0 = adjc + (size_t)(nodeBase + rA) * NH;
        const int* a1 = adjc + (size_t)(nodeBase + rB) * NH;
#pragma unroll
        for (int hh = 0; hh < NH; ++hh) { idxA[hh] = a0[hh]; idxB[hh] = a1[hh]; }
    }

    // B fragments: coalesced preload (fragment-ordered Wt), then pinned resident.
    short8v bfrag[KSTEPS];
    {
        const short8v* wp = (const short8v*)(Wt) + (size_t)wave * 64 + lane;
#pragma unroll
        for (int s = 0; s < KSTEPS; ++s) bfrag[s] = wp[(size_t)s * 256];
    }
#pragma unroll
    for (int s = 0; s < KSTEPS; ++s)
        asm volatile("" : "+v"(bfrag[s]));   // opaque: cannot be remat'd/sunk

    f32x4 acc[4];
#pragma unroll
    for (int m = 0; m < 4; ++m) acc[m] = (f32x4){0.f, 0.f, 0.f, 0.f};

#define STAGE(BUF, HH)                                                         \
    do {                                                                       \
        gload_lds16(h + (size_t)idxA[HH] * F + sswz * 8,                       \
                    (char*)tile + (BUF) * 8192 + (2 * wave) * 1024);           \
        gload_lds16(h + (size_t)idxB[HH] * F + sswz * 8,                       \
                    (char*)tile + (BUF) * 8192 + (2 * wave + 1) * 1024);       \
    } while (0)

#define COMPUTE(BUF, HH)                                                       \
    _Pragma("unroll")                                                          \
    for (int m = 0; m < 4; ++m) {                                              \
        _Pragma("unroll")                                                      \
        for (int kh = 0; kh < 2; ++kh) {                                       \
            const short8v a = *(const short8v*)((char*)tile + (BUF) * 8192     \
                + (m * 16 + l16) * 128 + (((kh * 4 + lg) ^ (l16 & 7)) * 16));  \
            acc[m] = __builtin_amdgcn_mfma_f32_16x16x32_bf16(                  \
                a, bfrag[(HH) * 2 + kh], acc[m], 0, 0, 0);                     \
        }                                                                      \
    }

    STAGE(0, 0);
    STAGE(1, 1);
    STAGE(2, 2);
#pragma unroll
    for (int hh = 0; hh < NH; ++hh) {
        if (hh <= NH - 3)      { asm volatile("s_waitcnt vmcnt(4)" ::: "memory"); }
        else if (hh == NH - 2) { asm volatile("s_waitcnt vmcnt(2)" ::: "memory"); }
        else                   { asm volatile("s_waitcnt vmcnt(0)" ::: "memory"); }
        __builtin_amdgcn_s_barrier();
        if (hh < NH - 3) STAGE((hh + 3) & 3, hh + 3);   // depth-3 prefetch
        COMPUTE(hh & 3, hh);
    }
#undef STAGE
#undef COMPUTE

    __syncthreads();   // all compute reads done before tile region is reused as T

    // Epilogue: transpose via LDS. D layout: row(node)=m*16+lg*4+r, col(o)=wave*16+l16
#pragma unroll
    for (int m = 0; m < 4; ++m)
#pragma unroll
        for (int r = 0; r < 4; ++r)
            T[m * 16 + lg * 4 + r][wave * 16 + l16] = acc[m][r];
    __syncthreads();

    const int t = threadIdx.x;
    const int nl = t >> 2, q = t & 3;                // 4 threads per node, 16 outputs each
    const int node = nodeBase + nl;
    float v[16];
#pragma unroll
    for (int i = 0; i < 16; ++i) v[i] = T[nl][q * 16 + i] + bias[q * 16 + i];

    if (FINAL) {
        float* out = (float*)outv;
        if (XBF) {
            const unsigned short* xb = (const unsigned short*)xres;
            unsigned short xr[16];
            *(short8v*)(xr)     = *(const short8v*)(xb + (size_t)node * F + q * 16);
            *(short8v*)(xr + 8) = *(const short8v*)(xb + (size_t)node * F + q * 16 + 8);
#pragma unroll
            for (int i4 = 0; i4 < 4; ++i4) {
                float4 ov;
                ov.x = v[i4 * 4 + 0] + bf2f(xr[i4 * 4 + 0]);
                ov.y = v[i4 * 4 + 1] + bf2f(xr[i4 * 4 + 1]);
                ov.z = v[i4 * 4 + 2] + bf2f(xr[i4 * 4 + 2]);
                ov.w = v[i4 * 4 + 3] + bf2f(xr[i4 * 4 + 3]);
                *(float4*)(out + (size_t)node * F + q * 16 + i4 * 4) = ov;
            }
        } else {
            const float* xf = (const float*)xres;
#pragma unroll
            for (int i4 = 0; i4 < 4; ++i4) {
                const float4 xv = *(const float4*)(xf + (size_t)node * F + q * 16 + i4 * 4);
                float4 ov;
                ov.x = v[i4 * 4 + 0] + xv.x; ov.y = v[i4 * 4 + 1] + xv.y;
                ov.z = v[i4 * 4 + 2] + xv.z; ov.w = v[i4 * 4 + 3] + xv.w;
                *(float4*)(out + (size_t)node * F + q * 16 + i4 * 4) = ov;
            }
        }
    } else {
        float s = 0.f, ss = 0.f;
#pragma unroll
        for (int i = 0; i < 16; ++i) { s += v[i]; ss += v[i] * v[i]; }
        s += __shfl_xor(s, 1); ss += __shfl_xor(ss, 1);
        s += __shfl_xor(s, 2); ss += __shfl_xor(ss, 2);
        const float mu = s * (1.0f / F);
        const float rstd = rsqrtf(ss * (1.0f / F) - mu * mu + LN_EPS);
        unsigned short* out = (unsigned short*)outv;
        unsigned short ob[16];
#pragma unroll
        for (int i = 0; i < 16; ++i) {
            const int o = q * 16 + i;
            const float y = (v[i] - mu) * rstd * lnw[o] + lnb[o];
            ob[i] = f2bf(silu_f(y));
        }
#pragma unroll
        for (int c = 0; c < 2; ++c)
            *(short8v*)(out + (size_t)node * F + q * 16 + c * 8) = *(short8v*)(ob + c * 8);
    }
}

extern "C" void kernel_launch(void* const* d_in, const int* in_sizes, int n_in,
                              void* d_out, int out_size, void* d_ws, size_t ws_size,
                              hipStream_t stream)
{
    const float* x    = (const float*)d_in[0];
    const int*   adjc = (const int*)d_in[1];
    const float* ln1w = (const float*)d_in[2];
    const float* ln1b = (const float*)d_in[3];
    const float* W1   = (const float*)d_in[4];
    const float* b1   = (const float*)d_in[5];
    const float* ln2w = (const float*)d_in[6];
    const float* ln2b = (const float*)d_in[7];
    const float* W2   = (const float*)d_in[8];
    const float* b2   = (const float*)d_in[9];
    float* out = (float*)d_out;

    const size_t hElems = (size_t)NNODES * F;
    unsigned short* h1  = (unsigned short*)d_ws;              // 25.2 MB bf16
    unsigned short* h2  = h1 + hElems;                        // 25.2 MB bf16
    unsigned short* Wt1 = h2 + hElems;                        // 144 KB
    unsigned short* Wt2 = Wt1 + F * K_TOT;                    // 144 KB
    unsigned short* xbf = Wt2 + F * K_TOT;                    // 25.2 MB bf16 (optional)
    const size_t need = (3 * hElems + 2 * (size_t)F * K_TOT) * sizeof(unsigned short);
    const bool useXbf = ws_size >= need;

    prep_wt<<<(F * K_TOT + 255) / 256, 256, 0, stream>>>(W1, W2, Wt1, Wt2);
    ln1_silu<<<NNODES / 16, 256, 0, stream>>>(x, ln1w, ln1b, h1, useXbf ? xbf : nullptr);
    gconv_mfma<0, 0><<<NNODES / 64, 256, 0, stream>>>(h1, adjc, Wt1, b1, ln2w, ln2b, nullptr, h2);
    if (useXbf)
        gconv_mfma<1, 1><<<NNODES / 64, 256, 0, stream>>>(h2, adjc, Wt2, b2, nullptr, nullptr, xbf, out);
    else
        gconv_mfma<1, 0><<<NNODES / 64, 256, 0, stream>>>(h2, adjc, Wt2, b2, nullptr, nullptr, x, out);
}